// Round 5
// baseline (43.755 us; speedup 1.0000x reference)
//
#include <hip/hip_runtime.h>

constexpr int   P     = 512;
constexpr int   W     = 256;
constexpr int   H     = 256;
constexpr float FXc   = 256.0f;
constexpr float FYc   = 256.0f;
constexpr float NEARc = 0.2f;
constexpr float BLUR  = 0.3f;
constexpr float LIMX  = 0.65f;
constexpr float LIMY  = 0.65f;

// d_out layout (floats)
constexpr int COLOR_OFF = 0;
constexpr int RADII_OFF = 196608;
constexpr int DEPTH_OFF = 197120;
constexpr int OPAC_OFF  = 262656;
constexpr int NT_OFF    = 328192;

// One block per image row; prep all 512 gaussians in-block (parallel across
// 256 CUs), cull to row survivors, stable-sort survivors by (depth,orig),
// blend front-to-back. Survivor records live in REGISTERS between cull and
// sorted scatter (no unsorted LDS buffer).
__global__ __launch_bounds__(256) void fused_row_kernel(
    const float* __restrict__ means3D, const float* __restrict__ scales,
    const float* __restrict__ rots,    const float* __restrict__ opacs,
    const float* __restrict__ cols,    const float* __restrict__ vm,
    const float* __restrict__ pm,      const float* __restrict__ bg,
    float* __restrict__ out)
{
    __shared__ float4 g4s[P * 3];      // sorted survivor records (48 B each)
    __shared__ float  sdep[P];
    __shared__ int    sorig[P];
    __shared__ int    sorg_s[P];
    __shared__ int    snt[P];
    __shared__ int    s_n;

    const int tid = threadIdx.x;
    const int row = blockIdx.x;
    const float fy = (float)row;

    if (tid == 0) s_n = 0;
    __syncthreads();

    float4 rec0[2], rec1[2], rec2[2];
    int    slot[2] = {-1, -1};
    float  rdep[2];
    int    rorig[2];

    // ---- prep 2 gaussians/thread; cull; reserve compacted slots ----
    #pragma unroll
    for (int k = 0; k < 2; ++k) {
        const int g = tid + k * 256;

        const float mx = means3D[g*3+0], my = means3D[g*3+1], mz = means3D[g*3+2];

        const float pv0 = vm[0]*mx + vm[1]*my + vm[2]*mz  + vm[3];
        const float pv1 = vm[4]*mx + vm[5]*my + vm[6]*mz  + vm[7];
        const float pv2 = vm[8]*mx + vm[9]*my + vm[10]*mz + vm[11];
        const float depth = pv2;

        const float ph0 = pm[0]*mx  + pm[1]*my  + pm[2]*mz  + pm[3];
        const float ph1 = pm[4]*mx  + pm[5]*my  + pm[6]*mz  + pm[7];
        const float ph3 = pm[12]*mx + pm[13]*my + pm[14]*mz + pm[15];
        const float pwn = 1.0f / (ph3 + 1e-7f);
        const float pp0 = ph0 * pwn, pp1 = ph1 * pwn;

        float q0 = rots[g*4+0], q1 = rots[g*4+1], q2 = rots[g*4+2], q3 = rots[g*4+3];
        const float qinv = 1.0f / sqrtf(q0*q0 + q1*q1 + q2*q2 + q3*q3);
        q0 *= qinv; q1 *= qinv; q2 *= qinv; q3 *= qinv;
        const float r = q0, x = q1, y = q2, z = q3;
        const float R00 = 1.f - 2.f*(y*y + z*z), R01 = 2.f*(x*y - r*z), R02 = 2.f*(x*z + r*y);
        const float R10 = 2.f*(x*y + r*z), R11 = 1.f - 2.f*(x*x + z*z), R12 = 2.f*(y*z - r*x);
        const float R20 = 2.f*(x*z - r*y), R21 = 2.f*(y*z + r*x), R22 = 1.f - 2.f*(x*x + y*y);

        const float s0 = scales[g*3+0], s1 = scales[g*3+1], s2 = scales[g*3+2];
        const float M00 = R00*s0, M01 = R01*s1, M02 = R02*s2;
        const float M10 = R10*s0, M11 = R11*s1, M12 = R12*s2;
        const float M20 = R20*s0, M21 = R21*s1, M22 = R22*s2;
        const float c00 = M00*M00 + M01*M01 + M02*M02;
        const float c01 = M00*M10 + M01*M11 + M02*M12;
        const float c02 = M00*M20 + M01*M21 + M02*M22;
        const float c11 = M10*M10 + M11*M11 + M12*M12;
        const float c12 = M10*M20 + M11*M21 + M12*M22;
        const float c22 = M20*M20 + M21*M21 + M22*M22;

        const float tz  = (fabsf(depth) < 1e-6f) ? 1e-6f : depth;
        const float txc = fminf(fmaxf(pv0 / tz, -LIMX), LIMX) * tz;
        const float tyc = fminf(fmaxf(pv1 / tz, -LIMY), LIMY) * tz;

        const float J00 = FXc / tz, J02 = -FXc * txc / (tz*tz);
        const float J11 = FYc / tz, J12 = -FYc * tyc / (tz*tz);

        const float T00 = J00*vm[0] + J02*vm[8];
        const float T01 = J00*vm[1] + J02*vm[9];
        const float T02 = J00*vm[2] + J02*vm[10];
        const float T10 = J11*vm[4] + J12*vm[8];
        const float T11 = J11*vm[5] + J12*vm[9];
        const float T12 = J11*vm[6] + J12*vm[10];

        const float V00 = T00*c00 + T01*c01 + T02*c02;
        const float V01 = T00*c01 + T01*c11 + T02*c12;
        const float V02 = T00*c02 + T01*c12 + T02*c22;
        const float V10 = T10*c00 + T11*c01 + T12*c02;
        const float V11 = T10*c01 + T11*c11 + T12*c12;
        const float V12 = T10*c02 + T11*c12 + T12*c22;

        const float a = V00*T00 + V01*T01 + V02*T02 + BLUR;
        const float b = V00*T10 + V01*T11 + V02*T12;
        const float c = V10*T10 + V11*T11 + V12*T12 + BLUR;
        const float det = a*c - b*b;

        const bool  valid = (depth > NEARc) && (det > 0.0f);
        const float det_s = valid ? det : 1.0f;
        const float ca =  c / det_s;
        const float cb = -b / det_s;
        const float cc =  a / det_s;

        const float op = opacs[g];
        const float rowrad2 = valid ? (2.0f * c * logf(255.0f * op)) * 1.0001f + 1e-4f
                                    : -1.0f;

        if (row == 0) {
            const float mid = 0.5f * (a + c);
            const float lam = mid + sqrtf(fmaxf(mid*mid - det, 0.1f));
            out[RADII_OFF + g] = valid ? ceilf(3.0f * sqrtf(lam)) : 0.0f;
        }

        const float px = ((pp0 + 1.0f) * (float)W - 1.0f) * 0.5f;
        const float py = ((pp1 + 1.0f) * (float)H - 1.0f) * 0.5f;

        const float dyv = py - fy;
        if (dyv * dyv <= rowrad2) {
            const int s = atomicAdd(&s_n, 1);
            slot[k]  = s;
            rdep[k]  = depth;
            rorig[k] = g;
            rec0[k] = make_float4(py, cb, px, ca);
            rec1[k] = make_float4(cc, op, depth, 0.0f);
            rec2[k] = make_float4(cols[g*3+0], cols[g*3+1], cols[g*3+2], 0.0f);
            sdep[s]  = depth;
            sorig[s] = g;
        }
        snt[tid + k * 256] = 0;
    }
    __syncthreads();
    const int n = s_n;

    // ---- stable rank from (depth, orig); scatter registers into g4s ----
    #pragma unroll
    for (int k = 0; k < 2; ++k) {
        if (slot[k] >= 0) {
            const float d = rdep[k];
            const int   o = rorig[k];
            int rank = 0;
            for (int j = 0; j < n; ++j) {
                const float dj = sdep[j];
                rank += (dj < d) || (dj == d && sorig[j] < o);
            }
            g4s[rank*3+0] = rec0[k];
            g4s[rank*3+1] = rec1[k];
            g4s[rank*3+2] = rec2[k];
            sorg_s[rank] = o;
        }
    }
    __syncthreads();

    // ---- front-to-back blend over sorted survivors ----
    const float fx = (float)tid;
    const bool lead = ((tid & 63) == 0);
    float T = 1.0f, ar = 0.f, ag = 0.f, ab = 0.f, ad = 0.f;

    for (int j = 0; j < n; ++j) {
        const float4 h  = g4s[j*3+0];      // py, cb, px, ca
        const float4 mm = g4s[j*3+1];      // cc, op, dep, -
        const float dx = h.z - fx;
        const float dy = h.x - fy;
        const float power = -0.5f*(h.w*dx*dx + mm.x*dy*dy) - h.y*dx*dy;
        const float alpha = fminf(0.99f, mm.y * __expf(power));
        const bool keep = (power <= 0.0f) && (alpha >= (1.0f/255.0f));

        const unsigned long long km = __ballot(keep);
        if (lead && km) atomicAdd(&snt[j], __popcll(km));

        if (keep) {
            const float4 cl = g4s[j*3+2];
            const float w = alpha * T;
            ar += w * cl.x; ag += w * cl.y; ab += w * cl.z; ad += w * mm.z;
            T *= (1.0f - alpha);
        }
    }
    __syncthreads();

    for (int t = tid; t < n; t += 256)
        if (snt[t]) atomicAdd(&out[NT_OFF + sorg_s[t]], (float)snt[t]);

    const int pix = row * W + tid;
    out[COLOR_OFF + 0*65536 + pix] = ar + T * bg[0];
    out[COLOR_OFF + 1*65536 + pix] = ag + T * bg[1];
    out[COLOR_OFF + 2*65536 + pix] = ab + T * bg[2];
    out[DEPTH_OFF + pix]           = ad;
    out[OPAC_OFF  + pix]           = 1.0f - T;
}

extern "C" void kernel_launch(void* const* d_in, const int* in_sizes, int n_in,
                              void* d_out, int out_size, void* d_ws, size_t ws_size,
                              hipStream_t stream) {
    const float* means3D = (const float*)d_in[0];
    const float* scales  = (const float*)d_in[1];
    const float* rots    = (const float*)d_in[2];
    const float* opacs   = (const float*)d_in[3];
    const float* cols    = (const float*)d_in[4];
    const float* vm      = (const float*)d_in[5];
    const float* pm      = (const float*)d_in[6];
    const float* bg      = (const float*)d_in[8];
    float* out = (float*)d_out;

    // n_touched accumulates via atomics -> zero every call (graph-safe).
    hipMemsetAsync((char*)d_out + (size_t)NT_OFF * 4, 0, P * 4, stream);
    fused_row_kernel<<<H, 256, 0, stream>>>(means3D, scales, rots, opacs, cols,
                                            vm, pm, bg, out);
}

// Round 6
// 28.424 us; speedup vs baseline: 1.5394x; 1.5394x over previous
//
#include <hip/hip_runtime.h>

constexpr int   P     = 512;
constexpr int   W     = 256;
constexpr int   H     = 256;
constexpr float FXc   = 256.0f;
constexpr float FYc   = 256.0f;
constexpr float NEARc = 0.2f;
constexpr float BLUR  = 0.3f;
constexpr float LIMX  = 0.65f;
constexpr float LIMY  = 0.65f;

// d_out layout (floats)
constexpr int COLOR_OFF = 0;
constexpr int RADII_OFF = 196608;
constexpr int DEPTH_OFF = 197120;
constexpr int OPAC_OFF  = 262656;
constexpr int NT_OFF    = 328192;

// One block per row (256 blocks, 4 waves each). Per block: prep all 512
// gaussians (parallel across CUs), row-cull + screen-x-cull, stable sort
// survivors by (depth, orig), then each wave compacts to the survivors
// overlapping its 64-px x-span and blends with register-prefetched LDS reads.
// Exactness: culled gaussians are provably keep=false for every pixel of the
// row/wave (power < ln(1/(255*op)) bound), contributing factor 1 to cumprod.
__global__ __launch_bounds__(256) void fused_row_kernel(
    const float* __restrict__ means3D, const float* __restrict__ scales,
    const float* __restrict__ rots,    const float* __restrict__ opacs,
    const float* __restrict__ cols,    const float* __restrict__ vm,
    const float* __restrict__ pm,      const float* __restrict__ bg,
    float* __restrict__ out)
{
    __shared__ float4 g4u[P * 3];        // unsorted survivor records
    __shared__ float4 g4s[P * 3];        // depth-sorted survivor records
    __shared__ float  sdep[P];
    __shared__ int    sorig[P];
    __shared__ int    sorg_s[P];
    __shared__ int    snt[P];
    __shared__ float2 sxc[P];            // (px, xrad2) in sorted order
    __shared__ int    wlist[4][P + 1];   // per-wave compacted rank lists
    __shared__ int    s_n;

    const int tid  = threadIdx.x;
    const int row  = blockIdx.x;
    const int wv   = tid >> 6;
    const int lane = tid & 63;
    const float fy = (float)row;

    if (tid == 0) s_n = 0;
    snt[tid] = 0; snt[tid + 256] = 0;
    __syncthreads();

    // ---- prep 2 gaussians/thread; row+screen-x cull into LDS ----
    #pragma unroll
    for (int k = 0; k < 2; ++k) {
        const int g = tid + k * 256;

        const float mx = means3D[g*3+0], my = means3D[g*3+1], mz = means3D[g*3+2];

        const float pv0 = vm[0]*mx + vm[1]*my + vm[2]*mz  + vm[3];
        const float pv1 = vm[4]*mx + vm[5]*my + vm[6]*mz  + vm[7];
        const float pv2 = vm[8]*mx + vm[9]*my + vm[10]*mz + vm[11];
        const float depth = pv2;

        const float ph0 = pm[0]*mx  + pm[1]*my  + pm[2]*mz  + pm[3];
        const float ph1 = pm[4]*mx  + pm[5]*my  + pm[6]*mz  + pm[7];
        const float ph3 = pm[12]*mx + pm[13]*my + pm[14]*mz + pm[15];
        const float pwn = 1.0f / (ph3 + 1e-7f);
        const float pp0 = ph0 * pwn, pp1 = ph1 * pwn;

        float q0 = rots[g*4+0], q1 = rots[g*4+1], q2 = rots[g*4+2], q3 = rots[g*4+3];
        const float qinv = 1.0f / sqrtf(q0*q0 + q1*q1 + q2*q2 + q3*q3);
        q0 *= qinv; q1 *= qinv; q2 *= qinv; q3 *= qinv;
        const float r = q0, x = q1, y = q2, z = q3;
        const float R00 = 1.f - 2.f*(y*y + z*z), R01 = 2.f*(x*y - r*z), R02 = 2.f*(x*z + r*y);
        const float R10 = 2.f*(x*y + r*z), R11 = 1.f - 2.f*(x*x + z*z), R12 = 2.f*(y*z - r*x);
        const float R20 = 2.f*(x*z - r*y), R21 = 2.f*(y*z + r*x), R22 = 1.f - 2.f*(x*x + y*y);

        const float s0 = scales[g*3+0], s1 = scales[g*3+1], s2 = scales[g*3+2];
        const float M00 = R00*s0, M01 = R01*s1, M02 = R02*s2;
        const float M10 = R10*s0, M11 = R11*s1, M12 = R12*s2;
        const float M20 = R20*s0, M21 = R21*s1, M22 = R22*s2;
        const float c00 = M00*M00 + M01*M01 + M02*M02;
        const float c01 = M00*M10 + M01*M11 + M02*M12;
        const float c02 = M00*M20 + M01*M21 + M02*M22;
        const float c11 = M10*M10 + M11*M11 + M12*M12;
        const float c12 = M10*M20 + M11*M21 + M12*M22;
        const float c22 = M20*M20 + M21*M21 + M22*M22;

        const float tz  = (fabsf(depth) < 1e-6f) ? 1e-6f : depth;
        const float txc = fminf(fmaxf(pv0 / tz, -LIMX), LIMX) * tz;
        const float tyc = fminf(fmaxf(pv1 / tz, -LIMY), LIMY) * tz;

        const float J00 = FXc / tz, J02 = -FXc * txc / (tz*tz);
        const float J11 = FYc / tz, J12 = -FYc * tyc / (tz*tz);

        const float T00 = J00*vm[0] + J02*vm[8];
        const float T01 = J00*vm[1] + J02*vm[9];
        const float T02 = J00*vm[2] + J02*vm[10];
        const float T10 = J11*vm[4] + J12*vm[8];
        const float T11 = J11*vm[5] + J12*vm[9];
        const float T12 = J11*vm[6] + J12*vm[10];

        const float V00 = T00*c00 + T01*c01 + T02*c02;
        const float V01 = T00*c01 + T01*c11 + T02*c12;
        const float V02 = T00*c02 + T01*c12 + T02*c22;
        const float V10 = T10*c00 + T11*c01 + T12*c02;
        const float V11 = T10*c01 + T11*c11 + T12*c12;
        const float V12 = T10*c02 + T11*c12 + T12*c22;

        const float a = V00*T00 + V01*T01 + V02*T02 + BLUR;
        const float b = V00*T10 + V01*T11 + V02*T12;
        const float c = V10*T10 + V11*T11 + V12*T12 + BLUR;
        const float det = a*c - b*b;

        const bool  valid = (depth > NEARc) && (det > 0.0f);
        const float det_s = valid ? det : 1.0f;
        const float conic_a =  c / det_s;
        const float conic_b = -b / det_s;
        const float conic_c =  a / det_s;

        const float op = opacs[g];
        const float L  = logf(255.0f * op);          // keep needs power >= -L
        const float rowrad2 = valid ? (2.0f * c * L) * 1.0001f + 1e-4f : -1.0f;
        const float xrad2   = valid ? (2.0f * a * L) * 1.0001f + 1e-4f : -1.0f;

        if (row == 0) {
            const float mid = 0.5f * (a + c);
            const float lam = mid + sqrtf(fmaxf(mid*mid - det, 0.1f));
            out[RADII_OFF + g] = valid ? ceilf(3.0f * sqrtf(lam)) : 0.0f;
        }

        const float px = ((pp0 + 1.0f) * (float)W - 1.0f) * 0.5f;
        const float py = ((pp1 + 1.0f) * (float)H - 1.0f) * 0.5f;

        const float dyv = py - fy;
        const float dxm = fmaxf(0.0f, fmaxf(-px, px - 255.0f));   // screen-x distance
        if (dyv * dyv <= rowrad2 && dxm * dxm <= xrad2) {
            const int s = atomicAdd(&s_n, 1);
            // pa,pb,pc chosen so power = pa*dx^2 + pc*dy^2 + pb*dx*dy
            g4u[s*3+0] = make_float4(py, -conic_b, px, -0.5f * conic_a);
            g4u[s*3+1] = make_float4(-0.5f * conic_c, op, depth, 0.0f);
            g4u[s*3+2] = make_float4(cols[g*3+0], cols[g*3+1], cols[g*3+2], xrad2);
            sdep[s]  = depth;
            sorig[s] = g;
        }
    }
    __syncthreads();
    const int n = s_n;

    // ---- stable rank-sort by (depth, orig); scatter; build (px,xrad2) list ----
    for (int t = tid; t < n; t += 256) {
        const float d = sdep[t];
        const int   o = sorig[t];
        int rank = 0;
        for (int j = 0; j < n; ++j) {
            const float dj = sdep[j];
            rank += (dj < d) || (dj == d && sorig[j] < o);
        }
        const float4 r0 = g4u[t*3+0], r1 = g4u[t*3+1], r2 = g4u[t*3+2];
        g4s[rank*3+0] = r0; g4s[rank*3+1] = r1; g4s[rank*3+2] = r2;
        sorg_s[rank] = o;
        sxc[rank] = make_float2(r0.z, r2.w);
    }
    __syncthreads();

    // ---- per-wave x-span compaction (order-preserving) ----
    const float wx0 = (float)(wv * 64);
    const float wx1 = wx0 + 63.0f;
    int cnt = 0;
    for (int tb = 0; tb < n; tb += 64) {
        const int t = tb + lane;
        bool take = false;
        if (t < n) {
            const float2 xr = sxc[t];
            const float dm = fmaxf(0.0f, fmaxf(wx0 - xr.x, xr.x - wx1));
            take = (dm * dm <= xr.y);
        }
        const unsigned long long mk = __ballot(take);
        if (take)
            wlist[wv][cnt + __popcll(mk & ((1ull << lane) - 1ull))] = t;
        cnt += __popcll(mk);
    }
    if (lane == 0) wlist[wv][cnt] = (cnt > 0) ? wlist[wv][cnt - 1] : 0;

    // ---- blend with register prefetch over wave-local survivor list ----
    const float fx = (float)tid;
    float T = 1.0f, ar = 0.f, ag = 0.f, ab = 0.f, ad = 0.f;

    if (cnt > 0) {
        int jc = wlist[wv][0];
        float4 h  = g4s[jc*3+0];
        float4 mm = g4s[jc*3+1];
        float4 cl = g4s[jc*3+2];
        for (int t = 0; t < cnt; ++t) {
            const int jn = wlist[wv][t + 1];
            const float4 hn  = g4s[jn*3+0];     // prefetch next survivor
            const float4 mmn = g4s[jn*3+1];
            const float4 cln = g4s[jn*3+2];

            const float dx = h.z - fx;
            const float dy = h.x - fy;
            const float pw = fmaf(h.w, dx*dx, fmaf(mm.x, dy*dy, h.y * dx * dy));
            const float alpha = fminf(0.99f, mm.y * __expf(pw));
            const bool keep = (pw <= 0.0f) && (alpha >= (1.0f / 255.0f));

            const unsigned long long km = __ballot(keep);
            if (lane == 0 && km) atomicAdd(&snt[jc], __popcll(km));

            const float ae  = keep ? alpha : 0.0f;
            const float wgt = ae * T;
            ar = fmaf(wgt, cl.x, ar); ag = fmaf(wgt, cl.y, ag);
            ab = fmaf(wgt, cl.z, ab); ad = fmaf(wgt, mm.z, ad);
            T *= (1.0f - ae);

            jc = jn; h = hn; mm = mmn; cl = cln;
        }
    }
    __syncthreads();

    // ---- n_touched: one device atomic per survivor with nonzero count ----
    for (int t = tid; t < n; t += 256)
        if (snt[t]) atomicAdd(&out[NT_OFF + sorg_s[t]], (float)snt[t]);

    const int pix = row * W + tid;
    out[COLOR_OFF + 0*65536 + pix] = ar + T * bg[0];
    out[COLOR_OFF + 1*65536 + pix] = ag + T * bg[1];
    out[COLOR_OFF + 2*65536 + pix] = ab + T * bg[2];
    out[DEPTH_OFF + pix]           = ad;
    out[OPAC_OFF  + pix]           = 1.0f - T;
}

extern "C" void kernel_launch(void* const* d_in, const int* in_sizes, int n_in,
                              void* d_out, int out_size, void* d_ws, size_t ws_size,
                              hipStream_t stream) {
    const float* means3D = (const float*)d_in[0];
    const float* scales  = (const float*)d_in[1];
    const float* rots    = (const float*)d_in[2];
    const float* opacs   = (const float*)d_in[3];
    const float* cols    = (const float*)d_in[4];
    const float* vm      = (const float*)d_in[5];
    const float* pm      = (const float*)d_in[6];
    const float* bg      = (const float*)d_in[8];
    float* out = (float*)d_out;

    // n_touched accumulates via atomics -> zero every call (graph-safe).
    hipMemsetAsync((char*)d_out + (size_t)NT_OFF * 4, 0, P * 4, stream);
    fused_row_kernel<<<H, 256, 0, stream>>>(means3D, scales, rots, opacs, cols,
                                            vm, pm, bg, out);
}

// Round 7
// 25.611 us; speedup vs baseline: 1.7084x; 1.1098x over previous
//
#include <hip/hip_runtime.h>

constexpr int   P     = 512;
constexpr int   W     = 256;
constexpr int   H     = 256;
constexpr float FXc   = 256.0f;
constexpr float FYc   = 256.0f;
constexpr float NEARc = 0.2f;
constexpr float BLUR  = 0.3f;
constexpr float LIMX  = 0.65f;
constexpr float LIMY  = 0.65f;

// d_out layout (floats)
constexpr int COLOR_OFF = 0;
constexpr int RADII_OFF = 196608;
constexpr int DEPTH_OFF = 197120;
constexpr int OPAC_OFF  = 262656;
constexpr int NT_OFF    = 328192;

// Single dispatch, one block per row. Per block: prep all 512 gaussians,
// row+screen-x cull, stable sort survivors by (depth, orig), per-wave x-span
// compaction, prefetched front-to-back blend. n_touched for gaussians
// {2*row, 2*row+1} is computed by THIS block via an exact bounding-box scan
// (keep() is independent of blending) and stored directly — no atomics, no
// zeroing pass, no second graph node.
__global__ __launch_bounds__(256) void fused_row_kernel(
    const float* __restrict__ means3D, const float* __restrict__ scales,
    const float* __restrict__ rots,    const float* __restrict__ opacs,
    const float* __restrict__ cols,    const float* __restrict__ vm,
    const float* __restrict__ pm,      const float* __restrict__ bg,
    float* __restrict__ out)
{
    __shared__ float4 g4u[P * 3];        // unsorted survivor records
    __shared__ float4 g4s[P * 3];        // depth-sorted survivor records
    __shared__ float  sdep[P];
    __shared__ int    sorig[P];
    __shared__ int    wlist[4][P + 1];   // per-wave compacted rank lists
    __shared__ float4 ntrec[2][2];       // params of gaussians 2b, 2b+1
    __shared__ int    s_cnt2[2];
    __shared__ int    s_n;

    const int tid  = threadIdx.x;
    const int row  = blockIdx.x;
    const int wv   = tid >> 6;
    const int lane = tid & 63;
    const float fy = (float)row;

    if (tid == 0) s_n = 0;
    if (tid < 2)  s_cnt2[tid] = 0;
    __syncthreads();

    // ---- prep 2 gaussians/thread; row+screen-x cull into LDS ----
    #pragma unroll
    for (int k = 0; k < 2; ++k) {
        const int g = tid + k * 256;

        const float mx = means3D[g*3+0], my = means3D[g*3+1], mz = means3D[g*3+2];

        const float pv0 = vm[0]*mx + vm[1]*my + vm[2]*mz  + vm[3];
        const float pv1 = vm[4]*mx + vm[5]*my + vm[6]*mz  + vm[7];
        const float pv2 = vm[8]*mx + vm[9]*my + vm[10]*mz + vm[11];
        const float depth = pv2;

        const float ph0 = pm[0]*mx  + pm[1]*my  + pm[2]*mz  + pm[3];
        const float ph1 = pm[4]*mx  + pm[5]*my  + pm[6]*mz  + pm[7];
        const float ph3 = pm[12]*mx + pm[13]*my + pm[14]*mz + pm[15];
        const float pwn = 1.0f / (ph3 + 1e-7f);
        const float pp0 = ph0 * pwn, pp1 = ph1 * pwn;

        float q0 = rots[g*4+0], q1 = rots[g*4+1], q2 = rots[g*4+2], q3 = rots[g*4+3];
        const float qinv = 1.0f / sqrtf(q0*q0 + q1*q1 + q2*q2 + q3*q3);
        q0 *= qinv; q1 *= qinv; q2 *= qinv; q3 *= qinv;
        const float r = q0, x = q1, y = q2, z = q3;
        const float R00 = 1.f - 2.f*(y*y + z*z), R01 = 2.f*(x*y - r*z), R02 = 2.f*(x*z + r*y);
        const float R10 = 2.f*(x*y + r*z), R11 = 1.f - 2.f*(x*x + z*z), R12 = 2.f*(y*z - r*x);
        const float R20 = 2.f*(x*z - r*y), R21 = 2.f*(y*z + r*x), R22 = 1.f - 2.f*(x*x + y*y);

        const float s0 = scales[g*3+0], s1 = scales[g*3+1], s2 = scales[g*3+2];
        const float M00 = R00*s0, M01 = R01*s1, M02 = R02*s2;
        const float M10 = R10*s0, M11 = R11*s1, M12 = R12*s2;
        const float M20 = R20*s0, M21 = R21*s1, M22 = R22*s2;
        const float c00 = M00*M00 + M01*M01 + M02*M02;
        const float c01 = M00*M10 + M01*M11 + M02*M12;
        const float c02 = M00*M20 + M01*M21 + M02*M22;
        const float c11 = M10*M10 + M11*M11 + M12*M12;
        const float c12 = M10*M20 + M11*M21 + M12*M22;
        const float c22 = M20*M20 + M21*M21 + M22*M22;

        const float tz  = (fabsf(depth) < 1e-6f) ? 1e-6f : depth;
        const float txc = fminf(fmaxf(pv0 / tz, -LIMX), LIMX) * tz;
        const float tyc = fminf(fmaxf(pv1 / tz, -LIMY), LIMY) * tz;

        const float J00 = FXc / tz, J02 = -FXc * txc / (tz*tz);
        const float J11 = FYc / tz, J12 = -FYc * tyc / (tz*tz);

        const float T00 = J00*vm[0] + J02*vm[8];
        const float T01 = J00*vm[1] + J02*vm[9];
        const float T02 = J00*vm[2] + J02*vm[10];
        const float T10 = J11*vm[4] + J12*vm[8];
        const float T11 = J11*vm[5] + J12*vm[9];
        const float T12 = J11*vm[6] + J12*vm[10];

        const float V00 = T00*c00 + T01*c01 + T02*c02;
        const float V01 = T00*c01 + T01*c11 + T02*c12;
        const float V02 = T00*c02 + T01*c12 + T02*c22;
        const float V10 = T10*c00 + T11*c01 + T12*c02;
        const float V11 = T10*c01 + T11*c11 + T12*c12;
        const float V12 = T10*c02 + T11*c12 + T12*c22;

        const float a = V00*T00 + V01*T01 + V02*T02 + BLUR;
        const float b = V00*T10 + V01*T11 + V02*T12;
        const float c = V10*T10 + V11*T11 + V12*T12 + BLUR;
        const float det = a*c - b*b;

        const bool  valid = (depth > NEARc) && (det > 0.0f);
        const float det_s = valid ? det : 1.0f;
        const float conic_a =  c / det_s;
        const float conic_b = -b / det_s;
        const float conic_c =  a / det_s;

        const float op = opacs[g];
        const float L  = logf(255.0f * op);          // keep needs power >= -L
        const float rowrad2 = valid ? (2.0f * c * L) * 1.0001f + 1e-4f : -1.0f;
        const float xrad2   = valid ? (2.0f * a * L) * 1.0001f + 1e-4f : -1.0f;

        if (row == 0) {
            const float mid = 0.5f * (a + c);
            const float lam = mid + sqrtf(fmaxf(mid*mid - det, 0.1f));
            out[RADII_OFF + g] = valid ? ceilf(3.0f * sqrtf(lam)) : 0.0f;
        }

        const float px = ((pp0 + 1.0f) * (float)W - 1.0f) * 0.5f;
        const float py = ((pp1 + 1.0f) * (float)H - 1.0f) * 0.5f;

        // stash params for this block's two n_touched gaussians
        if ((g >> 1) == row) {
            const int e = g & 1;
            ntrec[e][0] = make_float4(px, py, -0.5f * conic_a, -conic_b);
            ntrec[e][1] = make_float4(-0.5f * conic_c, op, xrad2, rowrad2);
        }

        const float dyv = py - fy;
        const float dxm = fmaxf(0.0f, fmaxf(-px, px - 255.0f));
        if (dyv * dyv <= rowrad2 && dxm * dxm <= xrad2) {
            const int s = atomicAdd(&s_n, 1);
            g4u[s*3+0] = make_float4(py, -conic_b, px, -0.5f * conic_a);
            g4u[s*3+1] = make_float4(-0.5f * conic_c, op, depth, xrad2);
            g4u[s*3+2] = make_float4(cols[g*3+0], cols[g*3+1], cols[g*3+2], 0.0f);
            sdep[s]  = depth;
            sorig[s] = g;
        }
    }
    __syncthreads();
    const int n = s_n;

    // ---- stable rank-sort by (depth, orig); scatter into g4s ----
    for (int t = tid; t < n; t += 256) {
        const float d = sdep[t];
        const int   o = sorig[t];
        int rank = 0;
        for (int j = 0; j < n; ++j) {
            const float dj = sdep[j];
            rank += (dj < d) || (dj == d && sorig[j] < o);
        }
        g4s[rank*3+0] = g4u[t*3+0];
        g4s[rank*3+1] = g4u[t*3+1];
        g4s[rank*3+2] = g4u[t*3+2];
    }
    __syncthreads();

    // ---- per-wave x-span compaction (order-preserving) ----
    const float wx0 = (float)(wv * 64);
    const float wx1 = wx0 + 63.0f;
    int cnt = 0;
    for (int tb = 0; tb < n; tb += 64) {
        const int t = tb + lane;
        bool take = false;
        if (t < n) {
            const float pxg = g4s[t*3+0].z;
            const float xr2 = g4s[t*3+1].w;
            const float dm  = fmaxf(0.0f, fmaxf(wx0 - pxg, pxg - wx1));
            take = (dm * dm <= xr2);
        }
        const unsigned long long mk = __ballot(take);
        if (take)
            wlist[wv][cnt + __popcll(mk & ((1ull << lane) - 1ull))] = t;
        cnt += __popcll(mk);
    }
    if (lane == 0) wlist[wv][cnt] = (cnt > 0) ? wlist[wv][cnt - 1] : 0;

    // ---- branchless blend with register prefetch ----
    const float fx = (float)tid;
    float T = 1.0f, ar = 0.f, ag = 0.f, ab = 0.f, ad = 0.f;

    if (cnt > 0) {
        int jc = wlist[wv][0];
        float4 h  = g4s[jc*3+0];
        float4 mm = g4s[jc*3+1];
        float4 cl = g4s[jc*3+2];
        for (int t = 0; t < cnt; ++t) {
            const int jn = wlist[wv][t + 1];
            const float4 hn  = g4s[jn*3+0];
            const float4 mmn = g4s[jn*3+1];
            const float4 cln = g4s[jn*3+2];

            const float dx = h.z - fx;
            const float dy = h.x - fy;
            const float pw = fmaf(h.w, dx*dx, fmaf(mm.x, dy*dy, h.y * dx * dy));
            const float alpha = fminf(0.99f, mm.y * __expf(pw));
            const bool keep = (pw <= 0.0f) && (alpha >= (1.0f / 255.0f));

            const float ae  = keep ? alpha : 0.0f;
            const float wgt = ae * T;
            ar = fmaf(wgt, cl.x, ar); ag = fmaf(wgt, cl.y, ag);
            ab = fmaf(wgt, cl.z, ab); ad = fmaf(wgt, mm.z, ad);
            T  = fmaf(-ae, T, T);

            h = hn; mm = mmn; cl = cln;
        }
    }

    const int pix = row * W + tid;
    out[COLOR_OFF + 0*65536 + pix] = ar + T * bg[0];
    out[COLOR_OFF + 1*65536 + pix] = ag + T * bg[1];
    out[COLOR_OFF + 2*65536 + pix] = ab + T * bg[2];
    out[DEPTH_OFF + pix]           = ad;
    out[OPAC_OFF  + pix]           = 1.0f - T;

    // ---- exact n_touched for gaussians 2*row, 2*row+1 via bbox scan ----
    // keep(g,px,py) is independent of blending; bbox (dx^2<=xrad2, dy^2<=rowrad2)
    // provably contains every keep pixel (marginal bounds of the conic quadratic).
    #pragma unroll
    for (int e = 0; e < 2; ++e) {
        const float4 r0 = ntrec[e][0], r1 = ntrec[e][1];
        const float pxg = r0.x, pyg = r0.y, pa = r0.z, pb = r0.w;
        const float pc = r1.x, opg = r1.y, rx2 = r1.z, ry2 = r1.w;
        int cc2 = 0;
        if (ry2 > 0.0f && rx2 > 0.0f) {
            const float ry = sqrtf(ry2), rx = sqrtf(rx2);
            const int y0 = max(0, (int)ceilf(pyg - ry));
            const int y1 = min(H - 1, (int)floorf(pyg + ry));
            const int x0 = max(0, (int)ceilf(pxg - rx));
            const int x1 = min(W - 1, (int)floorf(pxg + rx));
            const int xx = x0 + tid;
            if (xx <= x1 && y0 <= y1) {
                const float dx = (float)xx - pxg;
                const float padx2 = pa * dx * dx;
                for (int yy = y0; yy <= y1; ++yy) {
                    const float dy = (float)yy - pyg;
                    const float pw = fmaf(pc, dy*dy, fmaf(pb, dx*dy, padx2));
                    const float alpha = fminf(0.99f, opg * __expf(pw));
                    cc2 += (pw <= 0.0f) && (alpha >= (1.0f / 255.0f));
                }
            }
        }
        #pragma unroll
        for (int off = 32; off; off >>= 1) cc2 += __shfl_down(cc2, off);
        if (lane == 0 && cc2) atomicAdd(&s_cnt2[e], cc2);
    }
    __syncthreads();
    if (tid < 2) out[NT_OFF + (row << 1) + tid] = (float)s_cnt2[tid];
}

extern "C" void kernel_launch(void* const* d_in, const int* in_sizes, int n_in,
                              void* d_out, int out_size, void* d_ws, size_t ws_size,
                              hipStream_t stream) {
    const float* means3D = (const float*)d_in[0];
    const float* scales  = (const float*)d_in[1];
    const float* rots    = (const float*)d_in[2];
    const float* opacs   = (const float*)d_in[3];
    const float* cols    = (const float*)d_in[4];
    const float* vm      = (const float*)d_in[5];
    const float* pm      = (const float*)d_in[6];
    const float* bg      = (const float*)d_in[8];
    float* out = (float*)d_out;

    fused_row_kernel<<<H, 256, 0, stream>>>(means3D, scales, rots, opacs, cols,
                                            vm, pm, bg, out);
}